// Round 6
// baseline (238.105 us; speedup 1.0000x reference)
//
#include <hip/hip_runtime.h>
#include <hip/hip_bf16.h>

typedef __attribute__((ext_vector_type(8))) short bf16x8;
typedef __attribute__((ext_vector_type(4))) float f32x4;
typedef __attribute__((ext_vector_type(2))) unsigned uint2v;

#define L_SEQ 512
#define N_IN 12
#define S_DIM 128
#define M_OUT 12
#define LPAD 40           // shorts per n-row (80B -> <=2-way banks)
#define KT_STRIDE (16*LPAD)

// RNE f32->bf16 (cold paths)
__device__ inline short f2bf(float f) {
    union { float f; unsigned u; } q; q.f = f;
    unsigned r = (q.u + 0x7fffu + ((q.u >> 16) & 1u)) >> 16;
    return (short)r;
}
// packed f32x2 -> 2xbf16 (RNE), one VALU op
__device__ inline unsigned cvtpk(float lo, float hi) {
    unsigned r;
    asm("v_cvt_pk_bf16_f32 %0, %1, %2" : "=v"(r) : "v"(lo), "v"(hi));
    return r;
}
// B-slot (kt,q,j) holds state row s = 32kt + 16(j>>2) + 4q + (j&3).
// D-slot (reg j') of the 16x16 tile rt covers s-row 16rt + 4q + j' -> maps to
// B-slot (kt=rt>>1, q, j=(rt&1)*4+j') of the SAME lane.  E2E-verified R4/R5.
__device__ inline int s_perm(int kt, int q, int j) {
    return 32 * kt + 16 * (j >> 2) + 4 * q + (j & 3);
}
// lgkm-only barrier: does NOT drain vmcnt (x prefetch stays in flight)
__device__ inline void block_sync() {
    asm volatile("s_waitcnt lgkmcnt(0)" ::: "memory");
    __builtin_amdgcn_s_barrier();
}

__global__ __launch_bounds__(512, 1)
void elman_kernel(const float* __restrict__ x,
                  const float* __restrict__ a0,
                  const float* __restrict__ U_w,
                  const float* __restrict__ U_b,
                  const float* __restrict__ W_w,
                  const float* __restrict__ W_b,
                  const float* __restrict__ V_w,
                  const float* __restrict__ V_b,
                  float* __restrict__ out)
{
    __shared__ __align__(16) short stx[2][4 * KT_STRIDE];

    const int tid  = threadIdx.x;
    const int w    = tid >> 6;        // wave 0..7 (2 per SIMD)
    const int l    = tid & 63;
    const int n    = l & 15;          // batch col / A-row index
    const int q    = l >> 4;
    const bool qodd = (q & 1);
    const int b0   = blockIdx.x * 16;
    const int row  = b0 + n;

    // ---- wave w owns output tile rt = w (s-rows [16w,16w+16)) ----
    const int c = w * 16 + n;         // this lane's output s-row
    bf16x8 wf0, wf1, wf2, wf3; bf16x8 uf;
    {
        #pragma unroll
        for (int j = 0; j < 8; ++j) {
            wf0[j] = f2bf(W_w[(size_t)s_perm((w + 0) & 3, q, j) * S_DIM + c]);
            wf1[j] = f2bf(W_w[(size_t)s_perm((w + 1) & 3, q, j) * S_DIM + c]);
            wf2[j] = f2bf(W_w[(size_t)s_perm((w + 2) & 3, q, j) * S_DIM + c]);
            wf3[j] = f2bf(W_w[(size_t)s_perm((w + 3) & 3, q, j) * S_DIM + c]);
            const int k = q * 8 + j;
            float v;
            if (k < N_IN)       v = U_w[(size_t)k * S_DIM + c];
            else if (k == N_IN) v = W_b[c] + U_b[c];   // bias via x-slot k=12 == 1.0
            else                v = 0.f;
            uf[j] = f2bf(v);
        }
    }

    // ---- stage a0 into buf0 in exchange layout ----
    for (int idx = tid; idx < 4 * 16 * 32; idx += 512) {
        const int kt = idx >> 9, r = (idx >> 5) & 15, qj = idx & 31;
        const int s = s_perm(kt, qj >> 3, qj & 7);
        stx[0][kt * KT_STRIDE + r * LPAD + qj] = f2bf(a0[(size_t)(b0 + r) * S_DIM + s]);
    }
    block_sync();

    const int fragoff = n * LPAD + q * 8;
    bf16x8 stB0 = *(const bf16x8*)&stx[0][((w + 0) & 3) * KT_STRIDE + fragoff];
    bf16x8 stB1 = *(const bf16x8*)&stx[0][((w + 1) & 3) * KT_STRIDE + fragoff];
    bf16x8 stB2 = *(const bf16x8*)&stx[0][((w + 2) & 3) * KT_STRIDE + fragoff];
    bf16x8 stB3 = *(const bf16x8*)&stx[0][((w + 3) & 3) * KT_STRIDE + fragoff];

    // ---- x stream (R4/R5-verified): lane supplies B k-slots q*8+j = x[row][t][q*8+j]
    const float* xpA = x + (size_t)row * L_SEQ * N_IN + (q & 1) * 8;
    const float* xpB = xpA + (qodd ? 0 : 4);
    float4 xa0 = *(const float4*)(xpA + 0 * N_IN), xb0 = *(const float4*)(xpB + 0 * N_IN);
    float4 xa1 = *(const float4*)(xpA + 1 * N_IN), xb1 = *(const float4*)(xpB + 1 * N_IN);
    float4 xa2 = *(const float4*)(xpA + 2 * N_IN), xb2 = *(const float4*)(xpB + 2 * N_IN);
    float4 xa3 = *(const float4*)(xpA + 3 * N_IN), xb3 = *(const float4*)(xpB + 3 * N_IN);

#define MAKE_XF(XF, XA, XB) do {                                                       \
    union { unsigned u[4]; bf16x8 v; } xu_;                                            \
    xu_.u[0] = cvtpk(XA.x, XA.y);                                                      \
    xu_.u[1] = cvtpk(XA.z, XA.w);                                                      \
    xu_.u[2] = qodd ? 0x00003F80u : cvtpk(XB.x, XB.y);  /* k==12 -> bf16(1.0) */       \
    xu_.u[3] = qodd ? 0u          : cvtpk(XB.z, XB.w);                                 \
    XF = xu_.v;                                                                        \
} while (0)

    // accU(0) = U . x(0) + bias; recycle slot0 with x(4)
    f32x4 accU;
    {
        bf16x8 xf; MAKE_XF(xf, xa0, xb0);
        f32x4 z = {0.f, 0.f, 0.f, 0.f};
        accU = __builtin_amdgcn_mfma_f32_16x16x32_bf16(uf, xf, z, 0, 0, 0);
        xa0 = *(const float4*)(xpA + 4 * N_IN);
        xb0 = *(const float4*)(xpB + 4 * N_IN);
    }

#define STEP(XA, XB, TT, TNEXT) do {                                                   \
    /* two 2-deep MFMA chains (halved dependent latency) */                            \
    f32x4 z_ = {0.f, 0.f, 0.f, 0.f};                                                   \
    f32x4 acc_a = __builtin_amdgcn_mfma_f32_16x16x32_bf16(wf0, stB0, accU, 0, 0, 0);   \
    f32x4 acc_b = __builtin_amdgcn_mfma_f32_16x16x32_bf16(wf2, stB2, z_,   0, 0, 0);   \
    acc_a = __builtin_amdgcn_mfma_f32_16x16x32_bf16(wf1, stB1, acc_a, 0, 0, 0);        \
    acc_b = __builtin_amdgcn_mfma_f32_16x16x32_bf16(wf3, stB3, acc_b, 0, 0, 0);        \
    /* independent: next-step U.x while W-chains drain */                              \
    {                                                                                  \
        bf16x8 xf_; MAKE_XF(xf_, XA, XB);                                              \
        const int tl_ = ((TNEXT) < L_SEQ) ? (TNEXT) : (L_SEQ - 1);                     \
        XA = *(const float4*)(xpA + (size_t)tl_ * N_IN);                               \
        XB = *(const float4*)(xpB + (size_t)tl_ * N_IN);                               \
        accU = __builtin_amdgcn_mfma_f32_16x16x32_bf16(uf, xf_, z_, 0, 0, 0);          \
    }                                                                                  \
    /* relu + pack own 16x16 D tile -> 8B of next-step B tile (same lane) */           \
    uint2v su_;                                                                        \
    su_.x = cvtpk(fmaxf(acc_a[0] + acc_b[0], 0.f), fmaxf(acc_a[1] + acc_b[1], 0.f));   \
    su_.y = cvtpk(fmaxf(acc_a[2] + acc_b[2], 0.f), fmaxf(acc_a[3] + acc_b[3], 0.f));   \
    *(uint2v*)&stx[(TT + 1) & 1][(w >> 1) * KT_STRIDE + fragoff + (w & 1) * 4] = su_;  \
    block_sync();                                                                      \
    const short* rd_ = &stx[(TT + 1) & 1][0];                                          \
    stB0 = *(const bf16x8*)&rd_[((w + 0) & 3) * KT_STRIDE + fragoff];                  \
    stB1 = *(const bf16x8*)&rd_[((w + 1) & 3) * KT_STRIDE + fragoff];                  \
    stB2 = *(const bf16x8*)&rd_[((w + 2) & 3) * KT_STRIDE + fragoff];                  \
    stB3 = *(const bf16x8*)&rd_[((w + 3) & 3) * KT_STRIDE + fragoff];                  \
} while (0)

    for (int t = 0; t < L_SEQ; t += 4) {
        STEP(xa1, xb1, t + 0, t + 5);
        STEP(xa2, xb2, t + 1, t + 6);
        STEP(xa3, xb3, t + 2, t + 7);
        STEP(xa0, xb0, t + 3, t + 8);
    }
#undef STEP
#undef MAKE_XF

    // ---- epilogue: yT = V^T @ aT_L + V_b.  Wave 0 (its li order == physical kt). ----
    if (w == 0) {
        f32x4 acc = {0.f, 0.f, 0.f, 0.f};
        #pragma unroll
        for (int li = 0; li < 4; ++li) {
            bf16x8 vf;
            #pragma unroll
            for (int j = 0; j < 8; ++j)
                vf[j] = (n < M_OUT)
                      ? f2bf(V_w[(size_t)s_perm(li, q, j) * M_OUT + n])
                      : (short)0;
            const bf16x8 stt = (li == 0) ? stB0 : (li == 1) ? stB1 : (li == 2) ? stB2 : stB3;
            acc = __builtin_amdgcn_mfma_f32_16x16x32_bf16(vf, stt, acc, 0, 0, 0);
        }
        #pragma unroll
        for (int j = 0; j < 4; ++j) {
            const int m = 4 * q + j;
            if (m < M_OUT)
                out[(size_t)row * M_OUT + m] = acc[j] + V_b[m];
        }
    }
}

extern "C" void kernel_launch(void* const* d_in, const int* in_sizes, int n_in,
                              void* d_out, int out_size, void* d_ws, size_t ws_size,
                              hipStream_t stream) {
    const float* x   = (const float*)d_in[0];
    const float* a0  = (const float*)d_in[1];
    const float* U_w = (const float*)d_in[2];
    const float* U_b = (const float*)d_in[3];
    const float* W_w = (const float*)d_in[4];
    const float* W_b = (const float*)d_in[5];
    const float* V_w = (const float*)d_in[6];
    const float* V_b = (const float*)d_in[7];
    float* out = (float*)d_out;

    hipLaunchKernelGGL(elman_kernel, dim3(4096 / 16), dim3(512), 0, stream,
                       x, a0, U_w, U_b, W_w, W_b, V_w, V_b, out);
}

// Round 7
// 122.139 us; speedup vs baseline: 1.9495x; 1.9495x over previous
//
#include <hip/hip_runtime.h>
#include <hip/hip_bf16.h>

typedef __attribute__((ext_vector_type(8))) short bf16x8;
typedef __attribute__((ext_vector_type(4))) float f32x4;

#define L_SEQ 512
#define N_IN 12
#define S_DIM 128
#define M_OUT 12
#define LPAD 40           // shorts per n-row (80B -> <=2-way banks)
#define KT_STRIDE (16*LPAD)

// RNE f32->bf16 (cold paths)
__device__ inline short f2bf(float f) {
    union { float f; unsigned u; } q; q.f = f;
    unsigned r = (q.u + 0x7fffu + ((q.u >> 16) & 1u)) >> 16;
    return (short)r;
}
// packed f32x2 -> 2xbf16 (RNE), one VALU op
__device__ inline unsigned cvtpk(float lo, float hi) {
    unsigned r;
    asm("v_cvt_pk_bf16_f32 %0, %1, %2" : "=v"(r) : "v"(lo), "v"(hi));
    return r;
}
// B-slot (kt,q,j) holds state row s = 32kt + 16(j>>2) + 4q + (j&3).
// Same-lane D->B chaining: E2E-verified R4/R5.
__device__ inline int s_perm(int kt, int q, int j) {
    return 32 * kt + 16 * (j >> 2) + 4 * q + (j & 3);
}
// lgkm-only barrier: does NOT drain vmcnt (helpers' x prefetch stays in flight)
__device__ inline void block_sync() {
    asm volatile("s_waitcnt lgkmcnt(0)" ::: "memory");
    __builtin_amdgcn_s_barrier();
}

__global__ __launch_bounds__(512, 1)
void elman_kernel(const float* __restrict__ x,
                  const float* __restrict__ a0,
                  const float* __restrict__ U_w,
                  const float* __restrict__ U_b,
                  const float* __restrict__ W_w,
                  const float* __restrict__ W_b,
                  const float* __restrict__ V_w,
                  const float* __restrict__ V_b,
                  float* __restrict__ out)
{
    __shared__ __align__(16) short stx[2][4 * KT_STRIDE];  // state exchange (ping-pong)
    __shared__ __align__(16) short xr[4][64 * 8];          // xf fragment ring (4 slots)

    const int tid  = threadIdx.x;
    const int w    = tid >> 6;        // waves 0..3 compute, 4..7 x-stage helpers
    const int l    = tid & 63;
    const int n    = l & 15;
    const int q    = l >> 4;
    const bool qodd = (q & 1);
    const int b0   = blockIdx.x * 16;
    const int row  = b0 + n;
    const int fragoff = n * LPAD + q * 8;

    const float* xpA = x + (size_t)row * L_SEQ * N_IN + (q & 1) * 8;
    const float* xpB = xpA + (qodd ? 0 : 4);

#define MAKE_XF(XF, XA, XB) do {                                                       \
    union { unsigned uu[4]; bf16x8 v; } xu_;                                           \
    xu_.uu[0] = cvtpk(XA.x, XA.y);                                                     \
    xu_.uu[1] = cvtpk(XA.z, XA.w);                                                     \
    xu_.uu[2] = qodd ? 0x00003F80u : cvtpk(XB.x, XB.y);  /* k==12 -> bf16(1.0) */      \
    xu_.uu[3] = qodd ? 0u          : cvtpk(XB.z, XB.w);                                \
    XF = xu_.v;                                                                        \
} while (0)

    // ---- compute waves: step-invariant W/U fragments (wave w owns s-rows [32w,32w+32)) ----
    bf16x8 wf[2][4]; bf16x8 uf[2];
    if (w < 4) {
        #pragma unroll
        for (int h = 0; h < 2; ++h) {
            const int c = (2 * w + h) * 16 + n;
            #pragma unroll
            for (int li = 0; li < 4; ++li) {
                const int kt = (w + li) & 3;
                #pragma unroll
                for (int j = 0; j < 8; ++j)
                    wf[h][li][j] = f2bf(W_w[(size_t)s_perm(kt, q, j) * S_DIM + c]);
            }
            #pragma unroll
            for (int j = 0; j < 8; ++j) {
                const int k = q * 8 + j;
                float v;
                if (k < N_IN)       v = U_w[(size_t)k * S_DIM + c];
                else if (k == N_IN) v = W_b[c] + U_b[c];   // bias via x-slot k=12 == 1.0
                else                v = 0.f;
                uf[h][j] = f2bf(v);
            }
        }
    }

    // ---- stage a0 into buf0 (exchange layout) ----
    for (int idx = tid; idx < 4 * 16 * 32; idx += 512) {
        const int kt = idx >> 9, r = (idx >> 5) & 15, qj = idx & 31;
        const int s = s_perm(kt, qj >> 3, qj & 7);
        stx[0][kt * KT_STRIDE + r * LPAD + qj] = f2bf(a0[(size_t)(b0 + r) * S_DIM + s]);
    }

    // ---- helper prologue: prestage xf(0), xf(1); load first in-flight pair ----
    float4 xa, xb;
    if (w >= 4) {
        const int h = w & 3;
        if (h < 2) {
            float4 pa = *(const float4*)(xpA + (size_t)h * N_IN);
            float4 pb = *(const float4*)(xpB + (size_t)h * N_IN);
            bf16x8 xf; MAKE_XF(xf, pa, pb);
            *(bf16x8*)&xr[h][l * 8] = xf;
        }
        const int sf = ((h + 2) & 3) + 2;   // h: 0->4, 1->5, 2->2, 3->3
        xa = *(const float4*)(xpA + (size_t)sf * N_IN);
        xb = *(const float4*)(xpB + (size_t)sf * N_IN);
    }
    block_sync();

    // ---- compute prologue ----
    bf16x8 stOwn, stf1, stf2, stf3, xfc;
    f32x4 accU0, accU1;
    if (w < 4) {
        const short* rd = &stx[0][0];
        stOwn = *(const bf16x8*)&rd[((w + 0) & 3) * KT_STRIDE + fragoff];
        stf1  = *(const bf16x8*)&rd[((w + 1) & 3) * KT_STRIDE + fragoff];
        stf2  = *(const bf16x8*)&rd[((w + 2) & 3) * KT_STRIDE + fragoff];
        stf3  = *(const bf16x8*)&rd[((w + 3) & 3) * KT_STRIDE + fragoff];
        bf16x8 xf0 = *(const bf16x8*)&xr[0][l * 8];
        xfc        = *(const bf16x8*)&xr[1][l * 8];
        f32x4 z = {0.f, 0.f, 0.f, 0.f};
        accU0 = __builtin_amdgcn_mfma_f32_16x16x32_bf16(uf[0], xf0, z, 0, 0, 0);
        accU1 = __builtin_amdgcn_mfma_f32_16x16x32_bf16(uf[1], xf0, z, 0, 0, 0);
    }

    // ---- main recurrence ----
    for (int t = 0; t < L_SEQ; t += 4) {
        #pragma unroll
        for (int u = 0; u < 4; ++u) {
            const int tt = t + u;
            if (w < 4) {
                f32x4 z = {0.f, 0.f, 0.f, 0.f};
                // 4 independent leading MFMAs (reg-resident operands) hide stf read latency
                f32x4 c0a = __builtin_amdgcn_mfma_f32_16x16x32_bf16(wf[0][0], stOwn, accU0, 0, 0, 0);
                f32x4 c1a = __builtin_amdgcn_mfma_f32_16x16x32_bf16(wf[1][0], stOwn, accU1, 0, 0, 0);
                accU0 = __builtin_amdgcn_mfma_f32_16x16x32_bf16(uf[0], xfc, z, 0, 0, 0);  // for tt+1
                accU1 = __builtin_amdgcn_mfma_f32_16x16x32_bf16(uf[1], xfc, z, 0, 0, 0);
                c0a = __builtin_amdgcn_mfma_f32_16x16x32_bf16(wf[0][1], stf1, c0a, 0, 0, 0);
                c1a = __builtin_amdgcn_mfma_f32_16x16x32_bf16(wf[1][1], stf1, c1a, 0, 0, 0);
                f32x4 c0b = __builtin_amdgcn_mfma_f32_16x16x32_bf16(wf[0][2], stf2, z, 0, 0, 0);
                f32x4 c1b = __builtin_amdgcn_mfma_f32_16x16x32_bf16(wf[1][2], stf2, z, 0, 0, 0);
                c0b = __builtin_amdgcn_mfma_f32_16x16x32_bf16(wf[0][3], stf3, c0b, 0, 0, 0);
                c1b = __builtin_amdgcn_mfma_f32_16x16x32_bf16(wf[1][3], stf3, c1b, 0, 0, 0);
                // relu + pack own 32-row D tile -> next-step B k-tile (same lane, s_perm)
                union { unsigned uu[4]; bf16x8 v; } su;
                su.uu[0] = cvtpk(fmaxf(c0a[0] + c0b[0], 0.f), fmaxf(c0a[1] + c0b[1], 0.f));
                su.uu[1] = cvtpk(fmaxf(c0a[2] + c0b[2], 0.f), fmaxf(c0a[3] + c0b[3], 0.f));
                su.uu[2] = cvtpk(fmaxf(c1a[0] + c1b[0], 0.f), fmaxf(c1a[1] + c1b[1], 0.f));
                su.uu[3] = cvtpk(fmaxf(c1a[2] + c1b[2], 0.f), fmaxf(c1a[3] + c1b[3], 0.f));
                stOwn = su.v;
                *(bf16x8*)&stx[(tt + 1) & 1][w * KT_STRIDE + fragoff] = stOwn;
            } else {
                // helper h acts when h == (u+2)&3: write xf(tt+2), load x(tt+6)
                if ((w & 3) == ((u + 2) & 3)) {
                    bf16x8 xf; MAKE_XF(xf, xa, xb);
                    *(bf16x8*)&xr[(tt + 2) & 3][l * 8] = xf;
                    const int s2 = (tt + 6 < L_SEQ) ? (tt + 6) : (L_SEQ - 1);
                    xa = *(const float4*)(xpA + (size_t)s2 * N_IN);
                    xb = *(const float4*)(xpB + (size_t)s2 * N_IN);
                }
            }
            block_sync();
            if (w < 4) {
                const short* rd = &stx[(tt + 1) & 1][0];
                stf1 = *(const bf16x8*)&rd[((w + 1) & 3) * KT_STRIDE + fragoff];
                stf2 = *(const bf16x8*)&rd[((w + 2) & 3) * KT_STRIDE + fragoff];
                stf3 = *(const bf16x8*)&rd[((w + 3) & 3) * KT_STRIDE + fragoff];
                xfc  = *(const bf16x8*)&xr[(tt + 2) & 3][l * 8];
            }
        }
    }

    // ---- epilogue: yT = V^T @ aT_L + V_b.  Wave 0 (its li order == physical kt). ----
    if (w == 0) {
        f32x4 acc = {0.f, 0.f, 0.f, 0.f};
        #pragma unroll
        for (int li = 0; li < 4; ++li) {
            bf16x8 vf;
            #pragma unroll
            for (int j = 0; j < 8; ++j)
                vf[j] = (n < M_OUT)
                      ? f2bf(V_w[(size_t)s_perm(li, q, j) * M_OUT + n])
                      : (short)0;
            const bf16x8 stt = (li == 0) ? stOwn : (li == 1) ? stf1 : (li == 2) ? stf2 : stf3;
            acc = __builtin_amdgcn_mfma_f32_16x16x32_bf16(vf, stt, acc, 0, 0, 0);
        }
        #pragma unroll
        for (int j = 0; j < 4; ++j) {
            const int m = 4 * q + j;
            if (m < M_OUT)
                out[(size_t)row * M_OUT + m] = acc[j] + V_b[m];
        }
    }
#undef MAKE_XF
}

extern "C" void kernel_launch(void* const* d_in, const int* in_sizes, int n_in,
                              void* d_out, int out_size, void* d_ws, size_t ws_size,
                              hipStream_t stream) {
    const float* x   = (const float*)d_in[0];
    const float* a0  = (const float*)d_in[1];
    const float* U_w = (const float*)d_in[2];
    const float* U_b = (const float*)d_in[3];
    const float* W_w = (const float*)d_in[4];
    const float* W_b = (const float*)d_in[5];
    const float* V_w = (const float*)d_in[6];
    const float* V_b = (const float*)d_in[7];
    float* out = (float*)d_out;

    hipLaunchKernelGGL(elman_kernel, dim3(4096 / 16), dim3(512), 0, stream,
                       x, a0, U_w, U_b, W_w, W_b, V_w, V_b, out);
}